// Round 4
// baseline (415.344 us; speedup 1.0000x reference)
//
#include <hip/hip_runtime.h>

// StochasticRegionalConvolution, NHWC-MFMA version.
// out[b,co,p,q] = coeff(p,q) * sum_{ci,kh,kw} x[b,ci,p+kh,q+kw] * W[co,ci,kh,kw]
//
// K1: coeff map (256x256 f32)                     -> d_ws[0, 256KB)
// K2: weight transform to MFMA A-frag order, bf16 -> d_ws[256KB, 328KB)
// K3: x transform NCHW f32 -> NHWC bf16 (ci-minor)-> d_ws[1MB, 1MB+134MB)
// K4: conv, implicit GEMM, B-frags loaded straight from NHWC global (no LDS).
// Fallback (small ws): round-3 LDS-staged kernel.

typedef short short8 __attribute__((ext_vector_type(8)));
typedef float floatx4 __attribute__((ext_vector_type(4)));
typedef unsigned int uint4v __attribute__((ext_vector_type(4)));

#define OUTR 62

__device__ inline unsigned f2bf_pack(float lo, float hi) {
    unsigned ul = __builtin_bit_cast(unsigned, lo);
    unsigned uh = __builtin_bit_cast(unsigned, hi);
    ul = (ul + 0x7FFFu + ((ul >> 16) & 1u)) >> 16;   // RNE
    uh = (uh + 0x7FFFu + ((uh >> 16) & 1u)) >> 16;
    return ul | (uh << 16);
}

__global__ void srconv_coeff_kernel(const int* __restrict__ h_idx,
                                    const int* __restrict__ w_idx,
                                    const float* __restrict__ lam,
                                    int T, float* __restrict__ coeff) {
    int p = blockIdx.x;
    int q = threadIdx.x;
    float c = 0.f;
    for (int t = 0; t < T; ++t) {
        int dh = p - h_idx[t];
        int dw = q - w_idx[t];
        if (dh >= 0 && dh < OUTR && dw >= 0 && dw < OUTR) c += lam[t];
    }
    coeff[(p << 8) + q] = c * (1.0f / 16.0f);
}

__global__ void srconv_wtrans_kernel(const float* __restrict__ wgt,
                                     uint4v* __restrict__ afrag) {
    int id = blockIdx.x * 256 + threadIdx.x;      // [0, 72*64)
    int l  = id & 63;
    int fi = id >> 6;                             // (kk*2+cb)*4 + m
    int m  = fi & 3;
    int cb = (fi >> 2) & 1;
    int kk = fi >> 3;
    int co  = m * 16 + (l & 15);
    int ci0 = cb * 32 + (l >> 4) * 8;
    float w[8];
#pragma unroll
    for (int j = 0; j < 8; ++j)
        w[j] = wgt[(co * 64 + ci0 + j) * 9 + kk];
    uint4v d;
    d.x = f2bf_pack(w[0], w[1]);
    d.y = f2bf_pack(w[2], w[3]);
    d.z = f2bf_pack(w[4], w[5]);
    d.w = f2bf_pack(w[6], w[7]);
    afrag[id] = d;
}

// NCHW f32 -> NHWC bf16. Block: one (b, row, 64-col slab); LDS transpose.
__global__ void srconv_xtrans_kernel(const float* __restrict__ x,
                                     uint4v* __restrict__ xt) {
    __shared__ float xsf[64][65];                 // +1 pad: conflict-free
    const int t   = threadIdx.x;
    const int blk = blockIdx.x;                   // b*1024 + r*4 + cblk
    const int b   = blk >> 10;
    const int r   = (blk >> 2) & 255;
    const int C0  = (blk & 3) << 6;

#pragma unroll
    for (int it = 0; it < 4; ++it) {              // 64ci x 64col f32, coalesced
        int u  = it * 256 + t;
        int ci = u >> 4;
        int c4 = (u & 15) << 2;
        const float4 v = *reinterpret_cast<const float4*>(
            x + (((b << 6) + ci) << 16) + (r << 8) + C0 + c4);
        xsf[ci][c4 + 0] = v.x;
        xsf[ci][c4 + 1] = v.y;
        xsf[ci][c4 + 2] = v.z;
        xsf[ci][c4 + 3] = v.w;
    }
    __syncthreads();
#pragma unroll
    for (int it = 0; it < 2; ++it) {              // pack 8 ci -> 16B, coalesced
        int v   = it * 256 + t;                   // [0,512): c = v>>3, oct = v&7
        int c   = v >> 3;
        int oct = v & 7;
        float w0 = xsf[oct * 8 + 0][c], w1 = xsf[oct * 8 + 1][c];
        float w2 = xsf[oct * 8 + 2][c], w3 = xsf[oct * 8 + 3][c];
        float w4 = xsf[oct * 8 + 4][c], w5 = xsf[oct * 8 + 5][c];
        float w6 = xsf[oct * 8 + 6][c], w7 = xsf[oct * 8 + 7][c];
        uint4v d;
        d.x = f2bf_pack(w0, w1);
        d.y = f2bf_pack(w2, w3);
        d.z = f2bf_pack(w4, w5);
        d.w = f2bf_pack(w6, w7);
        int pix = (((b << 8) + r) << 8) + C0 + c;
        xt[pix * 8 + oct] = d;
    }
}

// Conv from NHWC bf16: no LDS, B-frags direct from global (L2-hot halo).
__launch_bounds__(256, 4)
__global__ void srconv_mfma_nhwc_kernel(const short8* __restrict__ xt,
                                        const float* __restrict__ coeff,
                                        const short8* __restrict__ afrag,
                                        float* __restrict__ out) {
    const int tid  = threadIdx.x;
    const int lane = tid & 63;
    const int wv   = tid >> 6;
    const int l15  = lane & 15;
    const int kg   = lane >> 4;

    const int tile = blockIdx.x;
    const int b    = blockIdx.y;
    const int P0   = (tile >> 4) << 4;
    const int Q0   = (tile & 15) << 4;

    float myc = coeff[((P0 + (tid >> 4)) << 8) + Q0 + (tid & 15)];
    if (__syncthreads_count(myc != 0.f) == 0) {
        int r = tid >> 4, c = tid & 15;
        float* op = out + ((b << 6) << 16) + ((P0 + r) << 8) + Q0 + c;
        for (int co = 0; co < 64; ++co) op[co << 16] = 0.f;
        return;
    }

    floatx4 acc[4][4];
#pragma unroll
    for (int m = 0; m < 4; ++m)
#pragma unroll
        for (int n = 0; n < 4; ++n) acc[m][n] = (floatx4){0.f, 0.f, 0.f, 0.f};

    const int w4   = wv << 2;
    const int qcol = Q0 + l15;

#pragma unroll
    for (int kk = 0; kk < 9; ++kk) {
        const int kh = kk / 3;
        const int kw = kk - kh * 3;
        const int pc = min(qcol + kw, 255);       // clamped halo: coeff==0 there
        int rowbase[4];
#pragma unroll
        for (int n = 0; n < 4; ++n) {
            int pr = min(P0 + w4 + n + kh, 255);
            rowbase[n] = ((((b << 8) + pr) << 8) + pc) << 3;   // short8 units
        }
#pragma unroll
        for (int cb = 0; cb < 2; ++cb) {
            short8 a[4];
#pragma unroll
            for (int m = 0; m < 4; ++m)
                a[m] = afrag[((((kk << 1) + cb) << 2) + m) * 64 + lane];
            short8 bf[4];
#pragma unroll
            for (int n = 0; n < 4; ++n)
                bf[n] = xt[rowbase[n] + (cb << 2) + kg];
#pragma unroll
            for (int m = 0; m < 4; ++m)
#pragma unroll
                for (int n = 0; n < 4; ++n)
                    acc[m][n] = __builtin_amdgcn_mfma_f32_16x16x32_bf16(
                        a[m], bf[n], acc[m][n], 0, 0, 0);
        }
    }

    // D layout (m89): col = lane&15 -> q, row = (lane>>4)*4+reg -> co
#pragma unroll
    for (int n = 0; n < 4; ++n) {
        int pr = P0 + w4 + n;
        float cf = coeff[(pr << 8) + Q0 + l15];
#pragma unroll
        for (int m = 0; m < 4; ++m)
#pragma unroll
            for (int reg = 0; reg < 4; ++reg) {
                int co = (m << 4) + (kg << 2) + reg;
                out[(((b << 6) + co) << 16) + (pr << 8) + Q0 + l15] =
                    acc[m][n][reg] * cf;
            }
    }
}

// ---------------- fallback (small d_ws): round-3 LDS-staged kernel ----------
__launch_bounds__(256, 2)
__global__ void srconv_mfma_lds_kernel(const float* __restrict__ x,
                                       const float* __restrict__ coeff,
                                       const short8* __restrict__ afrag,
                                       float* __restrict__ out) {
    __shared__ __align__(16) short xs[18 * 18 * 64];

    const int tid  = threadIdx.x;
    const int lane = tid & 63;
    const int wv   = tid >> 6;
    const int l15  = lane & 15;
    const int kg   = lane >> 4;
    const int tile = blockIdx.x;
    const int b    = blockIdx.y;
    const int P0   = (tile >> 4) << 4;
    const int Q0   = (tile & 15) << 4;

    float myc = coeff[((P0 + (tid >> 4)) << 8) + Q0 + (tid & 15)];
    if (__syncthreads_count(myc != 0.f) == 0) {
        int r = tid >> 4, c = tid & 15;
        float* op = out + ((b << 6) << 16) + ((P0 + r) << 8) + Q0 + c;
        for (int co = 0; co < 64; ++co) op[co << 16] = 0.f;
        return;
    }

    for (int idx = tid; idx < 8 * 18 * 18; idx += 256) {
        int cp8 = idx / (18 * 18);
        int rem = idx - cp8 * (18 * 18);
        int row = rem / 18;
        int col = rem - row * 18;
        int gr = min(P0 + row, 255);
        int gc = min(Q0 + col, 255);
        const float* xp = x + (((b << 6) + (cp8 << 3)) << 16) + (gr << 8) + gc;
        uint4v d;
        d.x = f2bf_pack(xp[0 << 16], xp[1 << 16]);
        d.y = f2bf_pack(xp[2 << 16], xp[3 << 16]);
        d.z = f2bf_pack(xp[4 << 16], xp[5 << 16]);
        d.w = f2bf_pack(xp[6 << 16], xp[7 << 16]);
        int off = ((row * 18 + col) << 6) + (cp8 << 3);
        off ^= (col & 7) << 3;
        *(uint4v*)(&xs[off]) = d;
    }
    __syncthreads();

    floatx4 acc[4][4];
#pragma unroll
    for (int m = 0; m < 4; ++m)
#pragma unroll
        for (int n = 0; n < 4; ++n) acc[m][n] = (floatx4){0.f, 0.f, 0.f, 0.f};

    const int w4 = wv << 2;
#pragma unroll
    for (int kk = 0; kk < 9; ++kk) {
        const int kh = kk / 3;
        const int kw = kk - kh * 3;
        const int col = kw + l15;
        const int cswz = (col & 7) << 3;
#pragma unroll
        for (int cb = 0; cb < 2; ++cb) {
            short8 a[4];
#pragma unroll
            for (int m = 0; m < 4; ++m)
                a[m] = afrag[((((kk << 1) + cb) << 2) + m) * 64 + lane];
            short8 bf[4];
#pragma unroll
            for (int n = 0; n < 4; ++n) {
                int lrow = w4 + n + kh;
                int off = (((lrow * 18 + col) << 6) + (cb << 5) + (kg << 3)) ^ cswz;
                bf[n] = *(const short8*)(&xs[off]);
            }
#pragma unroll
            for (int m = 0; m < 4; ++m)
#pragma unroll
                for (int n = 0; n < 4; ++n)
                    acc[m][n] = __builtin_amdgcn_mfma_f32_16x16x32_bf16(
                        a[m], bf[n], acc[m][n], 0, 0, 0);
        }
    }

#pragma unroll
    for (int n = 0; n < 4; ++n) {
        int pr = P0 + w4 + n;
        float cf = coeff[(pr << 8) + Q0 + l15];
#pragma unroll
        for (int m = 0; m < 4; ++m)
#pragma unroll
            for (int reg = 0; reg < 4; ++reg) {
                int co = (m << 4) + (kg << 2) + reg;
                out[(((b << 6) + co) << 16) + (pr << 8) + Q0 + l15] =
                    acc[m][n][reg] * cf;
            }
    }
}

extern "C" void kernel_launch(void* const* d_in, const int* in_sizes, int n_in,
                              void* d_out, int out_size, void* d_ws, size_t ws_size,
                              hipStream_t stream) {
    const float* x     = (const float*)d_in[0];
    const float* wgt   = (const float*)d_in[1];
    const int*   h_idx = (const int*)d_in[2];
    const int*   w_idx = (const int*)d_in[3];
    const float* lam   = (const float*)d_in[4];
    float*       out   = (float*)d_out;
    float*       coeff = (float*)d_ws;                        // 256 KB
    char*        af_b  = (char*)d_ws + 65536 * sizeof(float); // 72 KB
    const int    T     = in_sizes[2];

    const size_t xt_off   = 1u << 20;                         // 1 MB
    const size_t xt_bytes = (size_t)16 * 256 * 256 * 64 * 2;  // 134,217,728

    srconv_coeff_kernel<<<256, 256, 0, stream>>>(h_idx, w_idx, lam, T, coeff);
    srconv_wtrans_kernel<<<18, 256, 0, stream>>>(wgt, (uint4v*)af_b);

    if (ws_size >= xt_off + xt_bytes) {
        uint4v* xt = (uint4v*)((char*)d_ws + xt_off);
        srconv_xtrans_kernel<<<16384, 256, 0, stream>>>(x, xt);
        srconv_mfma_nhwc_kernel<<<dim3(256, 16), 256, 0, stream>>>(
            (const short8*)xt, coeff, (const short8*)af_b, out);
    } else {
        srconv_mfma_lds_kernel<<<dim3(256, 16), 256, 0, stream>>>(
            x, coeff, (const short8*)af_b, out);
    }
}